// Round 5
// baseline (107.065 us; speedup 1.0000x reference)
//
#include <hip/hip_runtime.h>
#include <hip/hip_bf16.h>
#include <stdint.h>

// Problem constants
#define B_    2
#define S_    2048
#define H_    16
#define DH_   64
#define D_    1024
#define ND3   3072      // 3*D
#define MTOT  4096      // B*S
#define L2E   1.4426950408889634f

typedef __attribute__((ext_vector_type(8))) short bf16x8;
typedef __attribute__((ext_vector_type(4))) short bf16x4;
typedef __attribute__((ext_vector_type(4))) float f32x4;

__device__ inline short f2bs(float f) {
  __hip_bfloat16 h = __float2bfloat16(f);
  return *reinterpret_cast<short*>(&h);
}
__device__ inline float bs2f(short s) {
  uint32_t u = ((uint32_t)(uint16_t)s) << 16;
  float f;
  __builtin_memcpy(&f, &u, 4);
  return f;
}

__device__ inline void gl_lds16(const void* g, void* l) {
  __builtin_amdgcn_global_load_lds(
      (const __attribute__((address_space(1))) uint32_t*)g,
      (__attribute__((address_space(3))) uint32_t*)l, 16, 0, 0);
}

// ---------------------------------------------------------------- x -> bf16
__global__ __launch_bounds__(256) void xcast_kernel(const float* __restrict__ X,
                                                    short* __restrict__ Xb) {
  const int i = (blockIdx.x * 256 + threadIdx.x) * 4;
  float4 v = *reinterpret_cast<const float4*>(X + i);
  bf16x4 o;
  o[0] = f2bs(v.x); o[1] = f2bs(v.y); o[2] = f2bs(v.z); o[3] = f2bs(v.w);
  *reinterpret_cast<bf16x4*>(Xb + i) = o;
}

// ------------------------------------------- W[k][n] -> Wt[n][k] bf16 (x3)
__global__ __launch_bounds__(256) void wcast_kernel(const float* __restrict__ Wq,
                                                    const float* __restrict__ Wk,
                                                    const float* __restrict__ Wv,
                                                    short* __restrict__ Wt) {
  __shared__ float t[32][33];
  const float* W = blockIdx.z == 0 ? Wq : (blockIdx.z == 1 ? Wk : Wv);
  short* out = Wt + (size_t)blockIdx.z * (D_ * D_);
  const int x = threadIdx.x, y = threadIdx.y;
  const int n0 = blockIdx.x * 32, k0 = blockIdx.y * 32;
#pragma unroll
  for (int i = 0; i < 4; ++i)
    t[y + 8 * i][x] = W[(size_t)(k0 + y + 8 * i) * D_ + n0 + x];
  __syncthreads();
#pragma unroll
  for (int i = 0; i < 4; ++i)
    out[(size_t)(n0 + y + 8 * i) * D_ + k0 + x] = f2bs(t[x][y + 8 * i]);
}

// ---------------------------------------------------------------- QKV GEMM
__global__ __launch_bounds__(256, 3) void qkv_gemm_kernel(
    const short* __restrict__ Xb, const short* __restrict__ Wt,
    const float* __restrict__ bq, const float* __restrict__ bk,
    const float* __restrict__ bv, short* __restrict__ QKV) {
  __shared__ short As[128 * 64];
  __shared__ short Bs[128 * 64];
  const int tid = threadIdx.x;
  const int lane = tid & 63, wid = tid >> 6;
  const int l15 = lane & 15, lg = lane >> 4;
  const int m0 = blockIdx.x * 128, n0 = blockIdx.y * 128;
  const int wr = (wid >> 1) * 64, wc = (wid & 1) * 64;

  f32x4 acc[4][4];
#pragma unroll
  for (int i = 0; i < 4; ++i)
#pragma unroll
    for (int j = 0; j < 4; ++j) acc[i][j] = (f32x4){0.f, 0.f, 0.f, 0.f};

  for (int k0 = 0; k0 < D_; k0 += 64) {
    __syncthreads();
#pragma unroll
    for (int it = 0; it < 4; ++it) {
      const int e = (it * 256 + tid) * 8;
      const int row = e >> 6, kk = e & 63;
      const int lb = (it * 256 + (tid & 192)) * 16;
      gl_lds16(Xb + (size_t)(m0 + row) * D_ + k0 + kk, (char*)As + lb);
      gl_lds16(Wt + (size_t)(n0 + row) * D_ + k0 + kk, (char*)Bs + lb);
    }
    __syncthreads();
#pragma unroll
    for (int ks = 0; ks < 2; ++ks) {
      bf16x8 a[4], b[4];
#pragma unroll
      for (int mt = 0; mt < 4; ++mt)
        a[mt] = *reinterpret_cast<const bf16x8*>(
            &As[(wr + mt * 16 + l15) * 64 + ks * 32 + lg * 8]);
#pragma unroll
      for (int nt = 0; nt < 4; ++nt)
        b[nt] = *reinterpret_cast<const bf16x8*>(
            &Bs[(wc + nt * 16 + l15) * 64 + ks * 32 + lg * 8]);
#pragma unroll
      for (int mt = 0; mt < 4; ++mt)
#pragma unroll
        for (int nt = 0; nt < 4; ++nt)
          acc[mt][nt] = __builtin_amdgcn_mfma_f32_16x16x32_bf16(
              a[mt], b[nt], acc[mt][nt], 0, 0, 0);
    }
  }
#pragma unroll
  for (int nt = 0; nt < 4; ++nt) {
    const int col = n0 + wc + nt * 16 + l15;
    float bias, qs;
    if (col < D_)            { bias = bq[col];          qs = 0.125f * L2E; }
    else if (col < 2 * D_)   { bias = bk[col - D_];     qs = 1.f; }
    else                     { bias = bv[col - 2 * D_]; qs = 1.f; }
#pragma unroll
    for (int mt = 0; mt < 4; ++mt)
#pragma unroll
      for (int r = 0; r < 4; ++r) {
        const int row = m0 + wr + mt * 16 + lg * 4 + r;
        QKV[(size_t)row * ND3 + col] = f2bs((acc[mt][nt][r] + bias) * qs);
      }
  }
}

// ----------------------------------------- V -> Vt[bh][dh][s] (head-major T)
__global__ __launch_bounds__(256) void vtrans_kernel(const short* __restrict__ QKV,
                                                     short* __restrict__ Vt) {
  __shared__ short t[64][72];
  const int st = blockIdx.x;
  const int h  = blockIdx.y;
  const int b  = blockIdx.z;
  const int tid = threadIdx.x;
  const short* src = QKV + (size_t)(b * S_ + st * 64) * ND3 + 2 * D_ + h * DH_;
#pragma unroll
  for (int it = 0; it < 2; ++it) {
    const int g = it * 256 + tid;
    const int row = g >> 3, c = (g & 7) * 8;
    bf16x8 v = *reinterpret_cast<const bf16x8*>(src + (size_t)row * ND3 + c);
    *reinterpret_cast<bf16x8*>(&t[row][c]) = v;
  }
  __syncthreads();
  short* dst = Vt + (size_t)(b * H_ + h) * DH_ * S_ + st * 64;
#pragma unroll
  for (int it = 0; it < 2; ++it) {
    const int g = it * 256 + tid;
    const int dh = g >> 3, sc = (g & 7) * 8;
    bf16x8 v;
#pragma unroll
    for (int i = 0; i < 8; ++i) v[i] = t[sc + i][dh];
    *reinterpret_cast<bf16x8*>(dst + (size_t)dh * S_ + sc) = v;
  }
}

// ----------------------------------------------------------- flash attention
// Swapped operands; softmax in-register; PV K=16 from registers.
// SPLIT=true: each (bh,qt) handled by 2 blocks (kv halves). lo writes
// unnormalized f32 partial at the FINAL output address (merge is in-place);
// hi writes bf16 partial + (m,l) per row to ws. SPLIT=false: direct write.
// All LDS fragment addresses and staging pointers hoisted out of the loop.
template <bool SPLIT>
__global__ __launch_bounds__(256, 4) void attn_kernel(
    const short* __restrict__ QKV, const short* __restrict__ Vtg,
    float* __restrict__ Out, short* __restrict__ Phi,
    float2* __restrict__ mlo, float2* __restrict__ mhi) {
  __shared__ short Ks[2][4096];
  __shared__ short Vs[2][4096];
  const int tid = threadIdx.x;
  const int lane = tid & 63, wid = tid >> 6;
  const int l15 = lane & 15, lg = lane >> 4;
  const int bh = blockIdx.x;
  const int qt = SPLIT ? (31 - (int)(blockIdx.y >> 1)) : (31 - (int)blockIdx.y);
  const int split = SPLIT ? (int)(blockIdx.y & 1) : 0;
  const int nsteps = qt + 1;
  const int half = nsteps >> 1;
  const int kb = SPLIT ? (split ? half : 0) : 0;
  const int ke = SPLIT ? (split ? nsteps : half) : nsteps;
  const int b = bh >> 4, h = bh & 15;
  const int q0 = qt * 64;
  const short* Qg = QKV + (size_t)b * S_ * ND3 + h * DH_;
  const short* Kg = QKV + (size_t)b * S_ * ND3 + D_ + h * DH_;
  const short* Vg = Vtg + (size_t)bh * DH_ * S_;

  // ---- loop-invariant addressing (hoisted) ----
  const int srow = tid >> 3;
  const int scol = ((tid & 7) ^ (srow & 7)) * 8;
  const char* kbase = (const char*)&Ks[0][0];
  const char* vbase = (const char*)&Vs[0][0];
  char* kdst = (char*)kbase + (tid & 192) * 16;
  char* vdst = (char*)vbase + (tid & 192) * 16;
  int ka[2];
#pragma unroll
  for (int ks = 0; ks < 2; ++ks)
    ka[ks] = l15 * 128 + ((((ks * 4 + lg)) ^ (l15 & 7)) << 4);
  int va[4];
#pragma unroll
  for (int ntk = 0; ntk < 4; ++ntk)
    va[ntk] = l15 * 128 + (((2 * ntk + (lg >> 1)) ^ (l15 & 7)) << 4) +
              ((lg & 1) << 3);
  const int qrow_g = q0 + wid * 16 + l15;

  // Q fragment (B-operand): lane holds Q[qrow_g][8*lg .. +7]
  bf16x8 qf[2];
#pragma unroll
  for (int ks = 0; ks < 2; ++ks)
    qf[ks] = *reinterpret_cast<const bf16x8*>(Qg + (size_t)qrow_g * ND3 +
                                              ks * 32 + lg * 8);

  f32x4 o[4];
#pragma unroll
  for (int i = 0; i < 4; ++i) o[i] = (f32x4){0.f, 0.f, 0.f, 0.f};
  float mrun = -1e30f, lsum = 0.f;

  // running global pointers (bumped per step)
  const short* kp = Kg + (size_t)(kb * 64 + srow) * ND3 + scol;
  const short* vp = Vg + (size_t)srow * S_ + kb * 64 + scol;

#define STAGE(bufoff)                                                        \
  {                                                                          \
    gl_lds16(kp, kdst + (bufoff));                                           \
    gl_lds16(kp + 32 * ND3, kdst + (bufoff) + 4096);                         \
    gl_lds16(vp, vdst + (bufoff));                                           \
    gl_lds16(vp + 32 * S_, vdst + (bufoff) + 4096);                          \
    kp += 64 * ND3;                                                          \
    vp += 64;                                                                \
  }

  if (kb < ke) {
    int curoff = 0;
    STAGE(0);
    __syncthreads();
    for (int kvt = kb; kvt < ke; ++kvt) {
      if (kvt + 1 < ke) STAGE(curoff ^ 8192);

      // S^T = K Q^T : s[nt][r] = S[q][kv = kvt*64 + nt*16 + lg*4 + r]
      f32x4 s[4];
#pragma unroll
      for (int i = 0; i < 4; ++i) s[i] = (f32x4){0.f, 0.f, 0.f, 0.f};
#pragma unroll
      for (int ks = 0; ks < 2; ++ks)
#pragma unroll
        for (int nt = 0; nt < 4; ++nt) {
          const bf16x8 kf = *reinterpret_cast<const bf16x8*>(
              kbase + curoff + ka[ks] + nt * 2048);
          s[nt] = __builtin_amdgcn_mfma_f32_16x16x32_bf16(kf, qf[ks], s[nt],
                                                          0, 0, 0);
        }
      if (kvt == qt) {  // causal mask (only the diag-owning block reaches it)
        const int kv0 = kvt * 64;
#pragma unroll
        for (int nt = 0; nt < 4; ++nt)
#pragma unroll
          for (int r = 0; r < 4; ++r)
            if (kv0 + nt * 16 + lg * 4 + r > qrow_g) s[nt][r] = -1e30f;
      }
      // row max (row q lives on 4 lanes)
      float pmax = -1e30f;
#pragma unroll
      for (int nt = 0; nt < 4; ++nt)
#pragma unroll
        for (int r = 0; r < 4; ++r) pmax = fmaxf(pmax, s[nt][r]);
      pmax = fmaxf(pmax, __shfl_xor(pmax, 16));
      pmax = fmaxf(pmax, __shfl_xor(pmax, 32));
      // T13 defer-max (log2 units)
      if (!__all(pmax <= mrun + 8.f)) {
        const float mnew = fmaxf(mrun, pmax);
        const float sc = exp2f(mrun - mnew);
        lsum *= sc;
#pragma unroll
        for (int nt = 0; nt < 4; ++nt)
#pragma unroll
          for (int r = 0; r < 4; ++r) o[nt][r] *= sc;
        mrun = mnew;
      }
      // P = exp2(s - m); pack bf16 (layout == PV B-frag ownership)
      float rowsum = 0.f;
      bf16x4 pk[4];
#pragma unroll
      for (int nt = 0; nt < 4; ++nt)
#pragma unroll
        for (int r = 0; r < 4; ++r) {
          const float p = exp2f(s[nt][r] - mrun);
          rowsum += p;
          pk[nt][r] = f2bs(p);
        }
      rowsum += __shfl_xor(rowsum, 16);
      rowsum += __shfl_xor(rowsum, 32);
      lsum += rowsum;

      // O^T += V^T P^T via 16x16x16 mfma, B-frag direct from registers
#pragma unroll
      for (int ntk = 0; ntk < 4; ++ntk)
#pragma unroll
        for (int ntd = 0; ntd < 4; ++ntd) {
          const bf16x4 vf = *reinterpret_cast<const bf16x4*>(
              vbase + curoff + va[ntk] + ntd * 2048);
          o[ntd] = __builtin_amdgcn_mfma_f32_16x16x16bf16_1k(vf, pk[ntk],
                                                             o[ntd], 0, 0, 0);
        }

      __syncthreads();
      curoff ^= 8192;
    }
  }
#undef STAGE

  // ---- epilogue ----
  if (!SPLIT) {
    const float inv = 1.f / lsum;
#pragma unroll
    for (int nt = 0; nt < 4; ++nt) {
      f32x4 v = {o[nt][0] * inv, o[nt][1] * inv, o[nt][2] * inv, o[nt][3] * inv};
      *reinterpret_cast<f32x4*>(
          &Out[((size_t)b * S_ + qrow_g) * D_ + h * DH_ + nt * 16 + lg * 4]) = v;
    }
  } else if (split == 0) {
    // lo: unnormalized f32 partial at the FINAL address (in-place merge)
#pragma unroll
    for (int nt = 0; nt < 4; ++nt)
      *reinterpret_cast<f32x4*>(
          &Out[((size_t)b * S_ + qrow_g) * D_ + h * DH_ + nt * 16 + lg * 4]) =
          o[nt];
    if (lg == 0) mlo[(size_t)bh * S_ + qrow_g] = make_float2(mrun, lsum);
  } else {
    // hi: unnormalized bf16 partial in tile layout
    const int tile = bh * 32 + qt;
    const int qrow = wid * 16 + l15;
#pragma unroll
    for (int nt = 0; nt < 4; ++nt) {
      bf16x4 pv;
#pragma unroll
      for (int r = 0; r < 4; ++r) pv[r] = f2bs(o[nt][r]);
      *reinterpret_cast<bf16x4*>(
          &Phi[((size_t)tile * 64 + qrow) * 64 + nt * 16 + lg * 4]) = pv;
    }
    if (lg == 0) mhi[(size_t)bh * S_ + qrow_g] = make_float2(mrun, lsum);
  }
}

// ------------------------------------------------------------- split merge
// In-place: Out currently holds the unnormalized lo partial at final layout.
__global__ __launch_bounds__(256) void merge_kernel(
    const short* __restrict__ Phi, const float2* __restrict__ mlo,
    const float2* __restrict__ mhi, float* __restrict__ Out) {
  const int tile = blockIdx.x;          // bh*32 + qt
  const int bh = tile >> 5, qt = tile & 31;
  const int b = bh >> 4, h = bh & 15;
  const int tid = threadIdx.x;
  const int q = tid >> 2;               // 0..63
  const int d0 = (tid & 3) * 16;
  const int qg = qt * 64 + q;
  const float2 a = mlo[(size_t)bh * S_ + qg];
  const float2 c = mhi[(size_t)bh * S_ + qg];
  const float m = fmaxf(a.x, c.x);
  const float wl = exp2f(a.x - m), wh = exp2f(c.x - m);
  const float inv = 1.f / (wl * a.y + wh * c.y);
  float* out = &Out[((size_t)b * S_ + qg) * D_ + h * DH_ + d0];
  const short* phi = &Phi[((size_t)tile * 64 + q) * 64 + d0];
#pragma unroll
  for (int j = 0; j < 4; ++j) {
    float4 lo4 = *reinterpret_cast<const float4*>(out + 4 * j);
    bf16x4 h4 = *reinterpret_cast<const bf16x4*>(phi + 4 * j);
    float4 r;
    r.x = (wl * lo4.x + wh * bs2f(h4[0])) * inv;
    r.y = (wl * lo4.y + wh * bs2f(h4[1])) * inv;
    r.z = (wl * lo4.z + wh * bs2f(h4[2])) * inv;
    r.w = (wl * lo4.w + wh * bs2f(h4[3])) * inv;
    *reinterpret_cast<float4*>(out + 4 * j) = r;
  }
}

// ---------------------------------------------------------------- launcher
extern "C" void kernel_launch(void* const* d_in, const int* in_sizes, int n_in,
                              void* d_out, int out_size, void* d_ws,
                              size_t ws_size, hipStream_t stream) {
  const float* x  = (const float*)d_in[0];
  const float* Wq = (const float*)d_in[1];
  const float* bq = (const float*)d_in[2];
  const float* Wk = (const float*)d_in[3];
  const float* bk = (const float*)d_in[4];
  const float* Wv = (const float*)d_in[5];
  const float* bv = (const float*)d_in[6];
  float* out = (float*)d_out;

  char* ws = (char*)d_ws;
  short* xb   = (short*)(ws);             //  8 MB: [4096][1024] bf16
  short* Wt   = (short*)(ws + 8388608);   //  6 MB: [3072][1024] bf16
  short* qkv  = (short*)(ws + 14680064);  // 24 MB: [4096][3072] bf16 (ends 38M)
  short* Vt   = xb;                       //  8 MB: reuses xb (dead after GEMM)
  short* Phi  = (short*)(ws + 39845888);  //  8 MB: hi partial bf16
  float2* mlo = (float2*)(ws + 48234496); // 512 KB
  float2* mhi = (float2*)(ws + 48758784); // 512 KB (ends ~49.3M)
  const bool can_split = ws_size >= (size_t)49283072;

  xcast_kernel<<<dim3(MTOT * D_ / (256 * 4)), dim3(256), 0, stream>>>(x, xb);
  wcast_kernel<<<dim3(32, 32, 3), dim3(32, 8), 0, stream>>>(Wq, Wk, Wv, Wt);
  qkv_gemm_kernel<<<dim3(MTOT / 128, ND3 / 128), dim3(256), 0, stream>>>(
      xb, Wt, bq, bk, bv, qkv);
  vtrans_kernel<<<dim3(S_ / 64, H_, B_), dim3(256), 0, stream>>>(qkv, Vt);
  if (can_split) {
    attn_kernel<true><<<dim3(B_ * H_, 2 * S_ / 64), dim3(256), 0, stream>>>(
        qkv, Vt, out, Phi, mlo, mhi);
    merge_kernel<<<dim3(B_ * H_ * S_ / 64), dim3(256), 0, stream>>>(
        Phi, mlo, mhi, out);
  } else {
    attn_kernel<false><<<dim3(B_ * H_, S_ / 64), dim3(256), 0, stream>>>(
        qkv, Vt, out, nullptr, nullptr, nullptr);
  }
}

// Round 6
// 105.930 us; speedup vs baseline: 1.0107x; 1.0107x over previous
//
#include <hip/hip_runtime.h>
#include <hip/hip_bf16.h>
#include <stdint.h>

// Problem constants
#define B_    2
#define S_    2048
#define H_    16
#define DH_   64
#define D_    1024
#define ND3   3072      // 3*D
#define MTOT  4096      // B*S
#define L2E   1.4426950408889634f

typedef __attribute__((ext_vector_type(8))) short bf16x8;
typedef __attribute__((ext_vector_type(4))) short bf16x4;
typedef __attribute__((ext_vector_type(4))) float f32x4;

__device__ inline short f2bs(float f) {
  __hip_bfloat16 h = __float2bfloat16(f);
  return *reinterpret_cast<short*>(&h);
}

// HW packed f32->bf16 (RNE): D.lo = bf16(a), D.hi = bf16(b). One VALU instr.
__device__ inline uint32_t cvtpk_bf16(float a, float b) {
  uint32_t r;
  asm("v_cvt_pk_bf16_f32 %0, %1, %2" : "=v"(r) : "v"(a), "v"(b));
  return r;
}

__device__ inline void gl_lds16(const void* g, void* l) {
  __builtin_amdgcn_global_load_lds(
      (const __attribute__((address_space(1))) uint32_t*)g,
      (__attribute__((address_space(3))) uint32_t*)l, 16, 0, 0);
}

// ---------------------------------------------------------------- x -> bf16
__global__ __launch_bounds__(256) void xcast_kernel(const float* __restrict__ X,
                                                    short* __restrict__ Xb) {
  const int i = (blockIdx.x * 256 + threadIdx.x) * 4;
  float4 v = *reinterpret_cast<const float4*>(X + i);
  bf16x4 o;
  o[0] = f2bs(v.x); o[1] = f2bs(v.y); o[2] = f2bs(v.z); o[3] = f2bs(v.w);
  *reinterpret_cast<bf16x4*>(Xb + i) = o;
}

// ------------------------------------------- W[k][n] -> Wt[n][k] bf16 (x3)
__global__ __launch_bounds__(256) void wcast_kernel(const float* __restrict__ Wq,
                                                    const float* __restrict__ Wk,
                                                    const float* __restrict__ Wv,
                                                    short* __restrict__ Wt) {
  __shared__ float t[32][33];
  const float* W = blockIdx.z == 0 ? Wq : (blockIdx.z == 1 ? Wk : Wv);
  short* out = Wt + (size_t)blockIdx.z * (D_ * D_);
  const int x = threadIdx.x, y = threadIdx.y;
  const int n0 = blockIdx.x * 32, k0 = blockIdx.y * 32;
#pragma unroll
  for (int i = 0; i < 4; ++i)
    t[y + 8 * i][x] = W[(size_t)(k0 + y + 8 * i) * D_ + n0 + x];
  __syncthreads();
#pragma unroll
  for (int i = 0; i < 4; ++i)
    out[(size_t)(n0 + y + 8 * i) * D_ + k0 + x] = f2bs(t[x][y + 8 * i]);
}

// ---------------------------------------------------------------- QKV GEMM
__global__ __launch_bounds__(256, 3) void qkv_gemm_kernel(
    const short* __restrict__ Xb, const short* __restrict__ Wt,
    const float* __restrict__ bq, const float* __restrict__ bk,
    const float* __restrict__ bv, short* __restrict__ QKV) {
  __shared__ short As[128 * 64];
  __shared__ short Bs[128 * 64];
  const int tid = threadIdx.x;
  const int lane = tid & 63, wid = tid >> 6;
  const int l15 = lane & 15, lg = lane >> 4;
  const int m0 = blockIdx.x * 128, n0 = blockIdx.y * 128;
  const int wr = (wid >> 1) * 64, wc = (wid & 1) * 64;

  f32x4 acc[4][4];
#pragma unroll
  for (int i = 0; i < 4; ++i)
#pragma unroll
    for (int j = 0; j < 4; ++j) acc[i][j] = (f32x4){0.f, 0.f, 0.f, 0.f};

  for (int k0 = 0; k0 < D_; k0 += 64) {
    __syncthreads();
#pragma unroll
    for (int it = 0; it < 4; ++it) {
      const int e = (it * 256 + tid) * 8;
      const int row = e >> 6, kk = e & 63;
      const int lb = (it * 256 + (tid & 192)) * 16;
      gl_lds16(Xb + (size_t)(m0 + row) * D_ + k0 + kk, (char*)As + lb);
      gl_lds16(Wt + (size_t)(n0 + row) * D_ + k0 + kk, (char*)Bs + lb);
    }
    __syncthreads();
#pragma unroll
    for (int ks = 0; ks < 2; ++ks) {
      bf16x8 a[4], b[4];
#pragma unroll
      for (int mt = 0; mt < 4; ++mt)
        a[mt] = *reinterpret_cast<const bf16x8*>(
            &As[(wr + mt * 16 + l15) * 64 + ks * 32 + lg * 8]);
#pragma unroll
      for (int nt = 0; nt < 4; ++nt)
        b[nt] = *reinterpret_cast<const bf16x8*>(
            &Bs[(wc + nt * 16 + l15) * 64 + ks * 32 + lg * 8]);
#pragma unroll
      for (int mt = 0; mt < 4; ++mt)
#pragma unroll
        for (int nt = 0; nt < 4; ++nt)
          acc[mt][nt] = __builtin_amdgcn_mfma_f32_16x16x32_bf16(
              a[mt], b[nt], acc[mt][nt], 0, 0, 0);
    }
  }
#pragma unroll
  for (int nt = 0; nt < 4; ++nt) {
    const int col = n0 + wc + nt * 16 + l15;
    float bias, qs;
    if (col < D_)            { bias = bq[col];          qs = 0.125f * L2E; }
    else if (col < 2 * D_)   { bias = bk[col - D_];     qs = 1.f; }
    else                     { bias = bv[col - 2 * D_]; qs = 1.f; }
#pragma unroll
    for (int mt = 0; mt < 4; ++mt)
#pragma unroll
      for (int r = 0; r < 4; ++r) {
        const int row = m0 + wr + mt * 16 + lg * 4 + r;
        QKV[(size_t)row * ND3 + col] = f2bs((acc[mt][nt][r] + bias) * qs);
      }
  }
}

// ----------------------------------------- V -> Vt[bh][dh][s] (head-major T)
__global__ __launch_bounds__(256) void vtrans_kernel(const short* __restrict__ QKV,
                                                     short* __restrict__ Vt) {
  __shared__ short t[64][72];
  const int st = blockIdx.x;
  const int h  = blockIdx.y;
  const int b  = blockIdx.z;
  const int tid = threadIdx.x;
  const short* src = QKV + (size_t)(b * S_ + st * 64) * ND3 + 2 * D_ + h * DH_;
#pragma unroll
  for (int it = 0; it < 2; ++it) {
    const int g = it * 256 + tid;
    const int row = g >> 3, c = (g & 7) * 8;
    bf16x8 v = *reinterpret_cast<const bf16x8*>(src + (size_t)row * ND3 + c);
    *reinterpret_cast<bf16x8*>(&t[row][c]) = v;
  }
  __syncthreads();
  short* dst = Vt + (size_t)(b * H_ + h) * DH_ * S_ + st * 64;
#pragma unroll
  for (int it = 0; it < 2; ++it) {
    const int g = it * 256 + tid;
    const int dh = g >> 3, sc = (g & 7) * 8;
    bf16x8 v;
#pragma unroll
    for (int i = 0; i < 8; ++i) v[i] = t[sc + i][dh];
    *reinterpret_cast<bf16x8*>(dst + (size_t)dh * S_ + sc) = v;
  }
}

// ----------------------------------------------------------- flash attention
// Swapped operands; in-register softmax; PV K=16 from registers; HW cvt_pk
// P-pack; T5 setprio around MFMA clusters; T13 defer-max; LPT block order.
__global__ __launch_bounds__(256, 5) void attn_kernel(
    const short* __restrict__ QKV, const short* __restrict__ Vtg,
    float* __restrict__ Out) {
  __shared__ short Ks[2][4096];
  __shared__ short Vs[2][4096];
  const int tid = threadIdx.x;
  const int lane = tid & 63, wid = tid >> 6;
  const int l15 = lane & 15, lg = lane >> 4;
  const int bh = blockIdx.x;
  const int qt = (S_ / 64 - 1) - (int)blockIdx.y;   // LPT: longest first
  const int b = bh >> 4, h = bh & 15;
  const int q0 = qt * 64;
  const short* Qg = QKV + (size_t)b * S_ * ND3 + h * DH_;
  const short* Kg = QKV + (size_t)b * S_ * ND3 + D_ + h * DH_;
  const short* Vg = Vtg + (size_t)bh * DH_ * S_;

  // ---- hoisted addressing ----
  const int srow = tid >> 3;
  const int scol = ((tid & 7) ^ (srow & 7)) * 8;
  const char* kbase = (const char*)&Ks[0][0];
  const char* vbase = (const char*)&Vs[0][0];
  char* kdst = (char*)kbase + (tid & 192) * 16;
  char* vdst = (char*)vbase + (tid & 192) * 16;
  int ka[2];
#pragma unroll
  for (int ks = 0; ks < 2; ++ks)
    ka[ks] = l15 * 128 + ((((ks * 4 + lg)) ^ (l15 & 7)) << 4);
  int va[4];
#pragma unroll
  for (int ntk = 0; ntk < 4; ++ntk)
    va[ntk] = l15 * 128 + (((2 * ntk + (lg >> 1)) ^ (l15 & 7)) << 4) +
              ((lg & 1) << 3);
  const int qrow_g = q0 + wid * 16 + l15;

  bf16x8 qf[2];
#pragma unroll
  for (int ks = 0; ks < 2; ++ks)
    qf[ks] = *reinterpret_cast<const bf16x8*>(Qg + (size_t)qrow_g * ND3 +
                                              ks * 32 + lg * 8);

  f32x4 o[4];
#pragma unroll
  for (int i = 0; i < 4; ++i) o[i] = (f32x4){0.f, 0.f, 0.f, 0.f};
  float mrun = -1e30f, lsum = 0.f;

  const short* kp = Kg + (size_t)srow * ND3 + scol;
  const short* vp = Vg + (size_t)srow * S_ + scol;

#define STAGE(bufoff)                                                        \
  {                                                                          \
    gl_lds16(kp, kdst + (bufoff));                                           \
    gl_lds16(kp + 32 * ND3, kdst + (bufoff) + 4096);                         \
    gl_lds16(vp, vdst + (bufoff));                                           \
    gl_lds16(vp + 32 * S_, vdst + (bufoff) + 4096);                          \
    kp += 64 * ND3;                                                          \
    vp += 64;                                                                \
  }

  int curoff = 0;
  STAGE(0);
  __syncthreads();

  for (int kvt = 0; kvt <= qt; ++kvt) {
    if (kvt < qt) STAGE(curoff ^ 8192);   // prefetch overlaps compute
    const char* kcur = kbase + curoff;
    const char* vcur = vbase + curoff;

    // S^T = K Q^T : s[nt][r] = S[q][kv = kvt*64 + nt*16 + lg*4 + r]
    f32x4 s[4];
#pragma unroll
    for (int i = 0; i < 4; ++i) s[i] = (f32x4){0.f, 0.f, 0.f, 0.f};
    __builtin_amdgcn_s_setprio(1);
#pragma unroll
    for (int ks = 0; ks < 2; ++ks)
#pragma unroll
      for (int nt = 0; nt < 4; ++nt) {
        const bf16x8 kf =
            *reinterpret_cast<const bf16x8*>(kcur + ka[ks] + nt * 2048);
        s[nt] = __builtin_amdgcn_mfma_f32_16x16x32_bf16(kf, qf[ks], s[nt],
                                                        0, 0, 0);
      }
    __builtin_amdgcn_s_setprio(0);

    if (kvt == qt) {  // causal mask on diagonal tile
      const int kv0 = kvt * 64;
#pragma unroll
      for (int nt = 0; nt < 4; ++nt)
#pragma unroll
        for (int r = 0; r < 4; ++r)
          if (kv0 + nt * 16 + lg * 4 + r > qrow_g) s[nt][r] = -1e30f;
    }
    // row max via max3-shaped tree (16 -> 8 ops), then 2 cross-lane steps
    float g0 = fmaxf(fmaxf(s[0][0], s[0][1]), s[0][2]);
    float g1 = fmaxf(fmaxf(s[0][3], s[1][0]), s[1][1]);
    float g2 = fmaxf(fmaxf(s[1][2], s[1][3]), s[2][0]);
    float g3 = fmaxf(fmaxf(s[2][1], s[2][2]), s[2][3]);
    float g4 = fmaxf(fmaxf(s[3][0], s[3][1]), s[3][2]);
    float h0 = fmaxf(fmaxf(g0, g1), g2);
    float h1 = fmaxf(fmaxf(g3, g4), s[3][3]);
    float pmax = fmaxf(h0, h1);
    pmax = fmaxf(pmax, __shfl_xor(pmax, 16));
    pmax = fmaxf(pmax, __shfl_xor(pmax, 32));
    // T13 defer-max (log2 units)
    if (!__all(pmax <= mrun + 8.f)) {
      const float mnew = fmaxf(mrun, pmax);
      const float sc = exp2f(mrun - mnew);
      lsum *= sc;
#pragma unroll
      for (int nt = 0; nt < 4; ++nt)
#pragma unroll
        for (int r = 0; r < 4; ++r) o[nt][r] *= sc;
      mrun = mnew;
    }
    // P = exp2(s - m); pack via HW cvt_pk (2 instrs per 4 values)
    float rowsum = 0.f;
    bf16x4 pk[4];
#pragma unroll
    for (int nt = 0; nt < 4; ++nt) {
      const float p0 = exp2f(s[nt][0] - mrun);
      const float p1 = exp2f(s[nt][1] - mrun);
      const float p2 = exp2f(s[nt][2] - mrun);
      const float p3 = exp2f(s[nt][3] - mrun);
      rowsum += (p0 + p1) + (p2 + p3);
      union { uint32_t u[2]; bf16x4 v; } pu;
      pu.u[0] = cvtpk_bf16(p0, p1);
      pu.u[1] = cvtpk_bf16(p2, p3);
      pk[nt] = pu.v;
    }
    rowsum += __shfl_xor(rowsum, 16);
    rowsum += __shfl_xor(rowsum, 32);
    lsum += rowsum;

    // O^T += V^T P^T via 16x16x16 mfma, B-frag direct from registers
    __builtin_amdgcn_s_setprio(1);
#pragma unroll
    for (int ntk = 0; ntk < 4; ++ntk)
#pragma unroll
      for (int ntd = 0; ntd < 4; ++ntd) {
        const bf16x4 vf =
            *reinterpret_cast<const bf16x4*>(vcur + va[ntk] + ntd * 2048);
        o[ntd] = __builtin_amdgcn_mfma_f32_16x16x16bf16_1k(vf, pk[ntk],
                                                           o[ntd], 0, 0, 0);
      }
    __builtin_amdgcn_s_setprio(0);

    __syncthreads();  // prefetch landed + all reads of cur done
    curoff ^= 8192;
  }
#undef STAGE

  // epilogue: O / lsum -> fp32 out [B,S,H,DH]
  const float inv = 1.f / lsum;
#pragma unroll
  for (int nt = 0; nt < 4; ++nt) {
    f32x4 v = {o[nt][0] * inv, o[nt][1] * inv, o[nt][2] * inv, o[nt][3] * inv};
    *reinterpret_cast<f32x4*>(
        &Out[((size_t)b * S_ + qrow_g) * D_ + h * DH_ + nt * 16 + lg * 4]) = v;
  }
}

// ---------------------------------------------------------------- launcher
extern "C" void kernel_launch(void* const* d_in, const int* in_sizes, int n_in,
                              void* d_out, int out_size, void* d_ws,
                              size_t ws_size, hipStream_t stream) {
  const float* x  = (const float*)d_in[0];
  const float* Wq = (const float*)d_in[1];
  const float* bq = (const float*)d_in[2];
  const float* Wk = (const float*)d_in[3];
  const float* bk = (const float*)d_in[4];
  const float* Wv = (const float*)d_in[5];
  const float* bv = (const float*)d_in[6];
  float* out = (float*)d_out;

  char* ws = (char*)d_ws;
  short* xb  = (short*)(ws);             //  8 MB: [4096][1024] bf16
  short* Wt  = (short*)(ws + 8388608);   //  6 MB: [3072][1024] bf16
  short* qkv = (short*)(ws + 14680064);  // 24 MB: [4096][3072] bf16
  short* Vt  = xb;                       //  8 MB: reuses xb (dead after GEMM)

  xcast_kernel<<<dim3(MTOT * D_ / (256 * 4)), dim3(256), 0, stream>>>(x, xb);
  wcast_kernel<<<dim3(32, 32, 3), dim3(32, 8), 0, stream>>>(Wq, Wk, Wv, Wt);
  qkv_gemm_kernel<<<dim3(MTOT / 128, ND3 / 128), dim3(256), 0, stream>>>(
      xb, Wt, bq, bk, bv, qkv);
  vtrans_kernel<<<dim3(S_ / 64, H_, B_), dim3(256), 0, stream>>>(qkv, Vt);
  attn_kernel<<<dim3(B_ * H_, S_ / 64), dim3(256), 0, stream>>>(qkv, Vt, out);
}

// Round 8
// 98.252 us; speedup vs baseline: 1.0897x; 1.0781x over previous
//
#include <hip/hip_runtime.h>
#include <hip/hip_bf16.h>
#include <stdint.h>

// Problem constants
#define B_    2
#define S_    2048
#define H_    16
#define DH_   64
#define D_    1024
#define ND3   3072      // 3*D
#define MTOT  4096      // B*S
#define L2E   1.4426950408889634f
#define MASKVAL (-3.0e38f)   // causal mask; must be << MINIT
#define MINIT   (-1.0e30f)   // running-max init

typedef __attribute__((ext_vector_type(8))) short bf16x8;
typedef __attribute__((ext_vector_type(4))) short bf16x4;
typedef __attribute__((ext_vector_type(4))) float f32x4;

__device__ inline short f2bs(float f) {
  __hip_bfloat16 h = __float2bfloat16(f);
  return *reinterpret_cast<short*>(&h);
}

__device__ inline void gl_lds16(const void* g, void* l) {
  __builtin_amdgcn_global_load_lds(
      (const __attribute__((address_space(1))) uint32_t*)g,
      (__attribute__((address_space(3))) uint32_t*)l, 16, 0, 0);
}

// ---------------------------------------------------------------- x -> bf16
__global__ __launch_bounds__(256) void xcast_kernel(const float* __restrict__ X,
                                                    short* __restrict__ Xb) {
  const int i = (blockIdx.x * 256 + threadIdx.x) * 4;
  float4 v = *reinterpret_cast<const float4*>(X + i);
  bf16x4 o;
  o[0] = f2bs(v.x); o[1] = f2bs(v.y); o[2] = f2bs(v.z); o[3] = f2bs(v.w);
  *reinterpret_cast<bf16x4*>(Xb + i) = o;
}

// ------------------------------------------- W[k][n] -> Wt[n][k] bf16 (x3)
__global__ __launch_bounds__(256) void wcast_kernel(const float* __restrict__ Wq,
                                                    const float* __restrict__ Wk,
                                                    const float* __restrict__ Wv,
                                                    short* __restrict__ Wt) {
  __shared__ float t[32][33];
  const float* W = blockIdx.z == 0 ? Wq : (blockIdx.z == 1 ? Wk : Wv);
  short* out = Wt + (size_t)blockIdx.z * (D_ * D_);
  const int x = threadIdx.x, y = threadIdx.y;
  const int n0 = blockIdx.x * 32, k0 = blockIdx.y * 32;
#pragma unroll
  for (int i = 0; i < 4; ++i)
    t[y + 8 * i][x] = W[(size_t)(k0 + y + 8 * i) * D_ + n0 + x];
  __syncthreads();
#pragma unroll
  for (int i = 0; i < 4; ++i)
    out[(size_t)(n0 + y + 8 * i) * D_ + k0 + x] = f2bs(t[x][y + 8 * i]);
}

// ---------------------------------------------------------------- QKV GEMM
__global__ __launch_bounds__(256, 3) void qkv_gemm_kernel(
    const short* __restrict__ Xb, const short* __restrict__ Wt,
    const float* __restrict__ bq, const float* __restrict__ bk,
    const float* __restrict__ bv, short* __restrict__ QKV) {
  __shared__ short As[128 * 64];
  __shared__ short Bs[128 * 64];
  const int tid = threadIdx.x;
  const int lane = tid & 63, wid = tid >> 6;
  const int l15 = lane & 15, lg = lane >> 4;
  const int m0 = blockIdx.x * 128, n0 = blockIdx.y * 128;
  const int wr = (wid >> 1) * 64, wc = (wid & 1) * 64;

  f32x4 acc[4][4];
#pragma unroll
  for (int i = 0; i < 4; ++i)
#pragma unroll
    for (int j = 0; j < 4; ++j) acc[i][j] = (f32x4){0.f, 0.f, 0.f, 0.f};

  for (int k0 = 0; k0 < D_; k0 += 64) {
    __syncthreads();
#pragma unroll
    for (int it = 0; it < 4; ++it) {
      const int e = (it * 256 + tid) * 8;
      const int row = e >> 6, kk = e & 63;
      const int lb = (it * 256 + (tid & 192)) * 16;
      gl_lds16(Xb + (size_t)(m0 + row) * D_ + k0 + kk, (char*)As + lb);
      gl_lds16(Wt + (size_t)(n0 + row) * D_ + k0 + kk, (char*)Bs + lb);
    }
    __syncthreads();
#pragma unroll
    for (int ks = 0; ks < 2; ++ks) {
      bf16x8 a[4], b[4];
#pragma unroll
      for (int mt = 0; mt < 4; ++mt)
        a[mt] = *reinterpret_cast<const bf16x8*>(
            &As[(wr + mt * 16 + l15) * 64 + ks * 32 + lg * 8]);
#pragma unroll
      for (int nt = 0; nt < 4; ++nt)
        b[nt] = *reinterpret_cast<const bf16x8*>(
            &Bs[(wc + nt * 16 + l15) * 64 + ks * 32 + lg * 8]);
#pragma unroll
      for (int mt = 0; mt < 4; ++mt)
#pragma unroll
        for (int nt = 0; nt < 4; ++nt)
          acc[mt][nt] = __builtin_amdgcn_mfma_f32_16x16x32_bf16(
              a[mt], b[nt], acc[mt][nt], 0, 0, 0);
    }
  }
#pragma unroll
  for (int nt = 0; nt < 4; ++nt) {
    const int col = n0 + wc + nt * 16 + l15;
    float bias, qs;
    if (col < D_)            { bias = bq[col];          qs = 0.125f * L2E; }
    else if (col < 2 * D_)   { bias = bk[col - D_];     qs = 1.f; }
    else                     { bias = bv[col - 2 * D_]; qs = 1.f; }
#pragma unroll
    for (int mt = 0; mt < 4; ++mt)
#pragma unroll
      for (int r = 0; r < 4; ++r) {
        const int row = m0 + wr + mt * 16 + lg * 4 + r;
        QKV[(size_t)row * ND3 + col] = f2bs((acc[mt][nt][r] + bias) * qs);
      }
  }
}

// ----------------------------------------- V -> Vt[bh][dh][s] (head-major T)
__global__ __launch_bounds__(256) void vtrans_kernel(const short* __restrict__ QKV,
                                                     short* __restrict__ Vt) {
  __shared__ short t[64][72];
  const int st = blockIdx.x;
  const int h  = blockIdx.y;
  const int b  = blockIdx.z;
  const int tid = threadIdx.x;
  const short* src = QKV + (size_t)(b * S_ + st * 64) * ND3 + 2 * D_ + h * DH_;
#pragma unroll
  for (int it = 0; it < 2; ++it) {
    const int g = it * 256 + tid;
    const int row = g >> 3, c = (g & 7) * 8;
    bf16x8 v = *reinterpret_cast<const bf16x8*>(src + (size_t)row * ND3 + c);
    *reinterpret_cast<bf16x8*>(&t[row][c]) = v;
  }
  __syncthreads();
  short* dst = Vt + (size_t)(b * H_ + h) * DH_ * S_ + st * 64;
#pragma unroll
  for (int it = 0; it < 2; ++it) {
    const int g = it * 256 + tid;
    const int dh = g >> 3, sc = (g & 7) * 8;
    bf16x8 v;
#pragma unroll
    for (int i = 0; i < 8; ++i) v[i] = t[sc + i][dh];
    *reinterpret_cast<bf16x8*>(dst + (size_t)dh * S_ + sc) = v;
  }
}

// ----------------------------------------------------------- flash attention
// r8 = r7 pipeline (QK one tile ahead, 3 LDS buffers, raw barrier + vmcnt
// drain) with the softmax math FIXED: row max IS shared across the 4 lanes
// of a row (2 shfl_xor) because the PV MFMA mixes P fragments from all 4
// lg-lanes of a row -> they must share one normalization scale. The lsum
// reduction stays deferred to the epilogue (per-lane partials are exact
// once mrun is row-shared).
__global__ __launch_bounds__(256, 3) void attn_kernel(
    const short* __restrict__ QKV, const short* __restrict__ Vtg,
    float* __restrict__ Out) {
  __shared__ short KV[3][8192];   // per buffer: K at +0 (8KB), V at +8KB
  const int tid = threadIdx.x;
  const int lane = tid & 63, wid = tid >> 6;
  const int l15 = lane & 15, lg = lane >> 4;
  const int bh = blockIdx.x;
  const int qt = (S_ / 64 - 1) - (int)blockIdx.y;   // LPT: longest first
  const int b = bh >> 4, h = bh & 15;
  const int q0 = qt * 64;
  const short* Qg = QKV + (size_t)b * S_ * ND3 + h * DH_;
  const short* Kg = QKV + (size_t)b * S_ * ND3 + D_ + h * DH_;
  const short* Vg = Vtg + (size_t)bh * DH_ * S_;

  // ---- hoisted addressing ----
  const int srow = tid >> 3;
  const int scol = ((tid & 7) ^ (srow & 7)) * 8;   // XOR-swizzled source chunk
  const char* kbase = (const char*)&KV[0][0];
  char* kdst = (char*)kbase + (tid & 192) * 16;
  char* vdst = kdst + 8192;
  int ka[2];
#pragma unroll
  for (int ks = 0; ks < 2; ++ks)
    ka[ks] = l15 * 128 + ((((ks * 4 + lg)) ^ (l15 & 7)) << 4);
  int va[4];
#pragma unroll
  for (int ntk = 0; ntk < 4; ++ntk)
    va[ntk] = 8192 + l15 * 128 + (((2 * ntk + (lg >> 1)) ^ (l15 & 7)) << 4) +
              ((lg & 1) << 3);
  const int qrow_g = q0 + wid * 16 + l15;

  bf16x8 qf[2];
#pragma unroll
  for (int ks = 0; ks < 2; ++ks)
    qf[ks] = *reinterpret_cast<const bf16x8*>(Qg + (size_t)qrow_g * ND3 +
                                              ks * 32 + lg * 8);

  f32x4 o[4];
#pragma unroll
  for (int i = 0; i < 4; ++i) o[i] = (f32x4){0.f, 0.f, 0.f, 0.f};
  float mrun = MINIT, lsum = 0.f;  // mrun row-shared; lsum per-lane partial

  // staging pointers track the next tile to stage
  const short* kp = Kg + (size_t)srow * ND3 + scol;
  const short* vp = Vg + (size_t)srow * S_ + scol;

#define STAGE_AT(OFF)                                                         \
  {                                                                           \
    gl_lds16(kp, kdst + (OFF));                                               \
    gl_lds16(kp + 32 * ND3, kdst + (OFF) + 4096);                             \
    gl_lds16(vp, vdst + (OFF));                                               \
    gl_lds16(vp + 32 * S_, vdst + (OFF) + 4096);                              \
    kp += 64 * ND3;                                                           \
    vp += 64;                                                                 \
  }

  int off0 = 0, off1 = 16384, off2 = 32768;  // cur(V) / next(K-ahead) / stage

  // prologue: stage tiles 0 (+1), drain, compute QK(0) into sA
  STAGE_AT(0);
  if (qt >= 1) STAGE_AT(16384);
  asm volatile("s_waitcnt vmcnt(0)" ::: "memory");
  __builtin_amdgcn_s_barrier();
  __builtin_amdgcn_sched_barrier(0);

  f32x4 sA[4], sB[4];
#pragma unroll
  for (int i = 0; i < 4; ++i) sA[i] = (f32x4){0.f, 0.f, 0.f, 0.f};
#pragma unroll
  for (int ks = 0; ks < 2; ++ks)
#pragma unroll
    for (int nt = 0; nt < 4; ++nt) {
      const bf16x8 kf =
          *reinterpret_cast<const bf16x8*>(kbase + ka[ks] + nt * 2048);
      sA[nt] = __builtin_amdgcn_mfma_f32_16x16x32_bf16(kf, qf[ks], sA[nt],
                                                       0, 0, 0);
    }

// One pipeline step: softmax+PV on tile T (scores in SC, V in buf off0),
// QK of tile T+1 into SN (K in buf off1), stage tile T+2 into buf off2.
#define STEP_BODY(T, SC, SN)                                                  \
  {                                                                           \
    const int T_ = (T);                                                       \
    if (T_ + 2 <= qt) STAGE_AT(off2);                                         \
    if (T_ + 1 <= qt) {                                                       \
      _Pragma("unroll") for (int i = 0; i < 4; ++i)                           \
          SN[i] = (f32x4){0.f, 0.f, 0.f, 0.f};                                \
      _Pragma("unroll") for (int ks = 0; ks < 2; ++ks)                        \
        _Pragma("unroll") for (int nt = 0; nt < 4; ++nt) {                    \
          const bf16x8 kf = *reinterpret_cast<const bf16x8*>(                 \
              kbase + off1 + ka[ks] + nt * 2048);                             \
          SN[nt] = __builtin_amdgcn_mfma_f32_16x16x32_bf16(kf, qf[ks],        \
                                                           SN[nt], 0, 0, 0);  \
        }                                                                     \
    }                                                                         \
    if (T_ == qt) { /* causal mask on diagonal tile */                        \
      const int kv0 = T_ * 64;                                                \
      _Pragma("unroll") for (int nt = 0; nt < 4; ++nt)                        \
        _Pragma("unroll") for (int r = 0; r < 4; ++r)                         \
          if (kv0 + nt * 16 + lg * 4 + r > qrow_g) SC[nt][r] = MASKVAL;       \
    }                                                                         \
    float g0 = fmaxf(fmaxf(SC[0][0], SC[0][1]), SC[0][2]);                    \
    float g1 = fmaxf(fmaxf(SC[0][3], SC[1][0]), SC[1][1]);                    \
    float g2 = fmaxf(fmaxf(SC[1][2], SC[1][3]), SC[2][0]);                    \
    float g3 = fmaxf(fmaxf(SC[2][1], SC[2][2]), SC[2][3]);                    \
    float g4 = fmaxf(fmaxf(SC[3][0], SC[3][1]), SC[3][2]);                    \
    float pmax = fmaxf(fmaxf(fmaxf(g0, g1), fmaxf(g2, g3)),                   \
                       fmaxf(g4, SC[3][3]));                                  \
    pmax = fmaxf(pmax, __shfl_xor(pmax, 16)); /* REQUIRED: PV mixes the */    \
    pmax = fmaxf(pmax, __shfl_xor(pmax, 32)); /* 4 lg-lanes of a row    */    \
    if (__any(pmax > mrun + 8.f)) { /* defer-max, log2 units */               \
      const float mnew = fmaxf(mrun, pmax);                                   \
      const float rsc = exp2f(mrun - mnew);                                   \
      lsum *= rsc;                                                            \
      _Pragma("unroll") for (int nt = 0; nt < 4; ++nt)                        \
        _Pragma("unroll") for (int r = 0; r < 4; ++r) o[nt][r] *= rsc;        \
      mrun = mnew;                                                            \
    }                                                                         \
    float rowsum = 0.f;                                                       \
    bf16x4 pk[4];                                                             \
    _Pragma("unroll") for (int nt = 0; nt < 4; ++nt)                          \
      _Pragma("unroll") for (int r = 0; r < 4; ++r) {                         \
        const float p = exp2f(SC[nt][r] - mrun);                              \
        rowsum += p;                                                          \
        pk[nt][r] = f2bs(p);                                                  \
      }                                                                       \
    lsum += rowsum; /* per-lane partial; reconciled in epilogue */            \
    _Pragma("unroll") for (int ntk = 0; ntk < 4; ++ntk)                       \
      _Pragma("unroll") for (int ntd = 0; ntd < 4; ++ntd) {                   \
        const bf16x4 vf = *reinterpret_cast<const bf16x4*>(                   \
            kbase + off0 + va[ntk] + ntd * 2048);                             \
        o[ntd] = __builtin_amdgcn_mfma_f32_16x16x16bf16_1k(vf, pk[ntk],       \
                                                           o[ntd], 0, 0, 0);  \
      }                                                                       \
    if (T_ < qt) {                                                            \
      asm volatile("s_waitcnt vmcnt(0)" ::: "memory");                        \
      __builtin_amdgcn_s_barrier();                                           \
      __builtin_amdgcn_sched_barrier(0);                                      \
    }                                                                         \
    const int otmp = off0; off0 = off1; off1 = off2; off2 = otmp;             \
  }

  for (int t = 0; t <= qt; t += 2) {
    STEP_BODY(t, sA, sB);
    if (t + 1 <= qt) STEP_BODY(t + 1, sB, sA);
  }
#undef STEP_BODY
#undef STAGE_AT

  // epilogue: sum the 4 per-lane lsum partials of each row (mrun is already
  // row-shared, so fac==1; kept general for safety), normalize, store.
  float mg = fmaxf(mrun, __shfl_xor(mrun, 16));
  mg = fmaxf(mg, __shfl_xor(mg, 32));
  const float fac = exp2f(mrun - mg);
  float ls = lsum * fac;
  ls += __shfl_xor(ls, 16);
  ls += __shfl_xor(ls, 32);
  const float inv = fac / ls;
#pragma unroll
  for (int nt = 0; nt < 4; ++nt) {
    f32x4 v = {o[nt][0] * inv, o[nt][1] * inv, o[nt][2] * inv, o[nt][3] * inv};
    *reinterpret_cast<f32x4*>(
        &Out[((size_t)b * S_ + qrow_g) * D_ + h * DH_ + nt * 16 + lg * 4]) = v;
  }
}

// ---------------------------------------------------------------- launcher
extern "C" void kernel_launch(void* const* d_in, const int* in_sizes, int n_in,
                              void* d_out, int out_size, void* d_ws,
                              size_t ws_size, hipStream_t stream) {
  const float* x  = (const float*)d_in[0];
  const float* Wq = (const float*)d_in[1];
  const float* bq = (const float*)d_in[2];
  const float* Wk = (const float*)d_in[3];
  const float* bk = (const float*)d_in[4];
  const float* Wv = (const float*)d_in[5];
  const float* bv = (const float*)d_in[6];
  float* out = (float*)d_out;

  char* ws = (char*)d_ws;
  short* xb  = (short*)(ws);             //  8 MB: [4096][1024] bf16
  short* Wt  = (short*)(ws + 8388608);   //  6 MB: [3072][1024] bf16
  short* qkv = (short*)(ws + 14680064);  // 24 MB: [4096][3072] bf16
  short* Vt  = xb;                       //  8 MB: reuses xb (dead after GEMM)

  xcast_kernel<<<dim3(MTOT * D_ / (256 * 4)), dim3(256), 0, stream>>>(x, xb);
  wcast_kernel<<<dim3(32, 32, 3), dim3(32, 8), 0, stream>>>(Wq, Wk, Wv, Wt);
  qkv_gemm_kernel<<<dim3(MTOT / 128, ND3 / 128), dim3(256), 0, stream>>>(
      xb, Wt, bq, bk, bv, qkv);
  vtrans_kernel<<<dim3(S_ / 64, H_, B_), dim3(256), 0, stream>>>(qkv, Vt);
  attn_kernel<<<dim3(B_ * H_, S_ / 64), dim3(256), 0, stream>>>(qkv, Vt, out);
}